// Round 1
// 212.590 us; speedup vs baseline: 1.1302x; 1.1302x over previous
//
#include <hip/hip_runtime.h>
#include <math.h>

// Problem constants
#define NN 2048      // nodes per modality
#define TWO_N 4096   // total nodes
#define BB 4         // batch
#define CC 64        // input feature dim
#define HD 128       // hidden dim
#define CANDCAP 32   // max top-k candidates per row after f32 margin filter
#define NE4 (4 * NN) // materialized hyperedges (inter edges handled inline)

// Layer-1 is computed in reordered form: relu(A (x W1)) == relu((A x) W1).
// So layer-1 edge/node stages aggregate the 64-dim raw features (half the
// gather bytes of the 128-dim y rows, and the gather working set f1/f2 = 4 MB
// is L2-resident), then gemm1 applies W1 + relu.
// All dense math is f32 (error ~2e-6 vs the 3e-5 slack); f64 kept only where
// selection exactness requires it (gR64 refine dots).

// ---------------------------------------------------------------------------
// 0) transpose W1/W2 once so gemm LDS staging is coalesced-read +
//    conflict-free-write. 16384 ids.
// ---------------------------------------------------------------------------
__global__ void k_prep(const float* __restrict__ W1, const float* __restrict__ W2,
                       float* __restrict__ W1T, float* __restrict__ W2T) {
    int id = blockIdx.x * 256 + threadIdx.x;   // 0..16383
    if (id < HD * CC) {
        int c = id >> 6, k = id & 63;
        W1T[(size_t)k * HD + c] = W1[id];      // W1T[k][c], k<64, c<128
    }
    {
        int c = id >> 7, k = id & 127;
        W2T[(size_t)k * HD + c] = W2[id];      // W2T[k][c], k<128, c<128
    }
}

// ---------------------------------------------------------------------------
// 1) batch-mean + L2-normalize. Also zeroes DV (prior launch => no race with
//    k_selref's atomicAdds; inter-edge +1 handled analytically in k_scan).
// ---------------------------------------------------------------------------
__global__ void k_mean_norm(const float* __restrict__ f1, const float* __restrict__ f2,
                            float* __restrict__ g32T, double* __restrict__ gR64,
                            int* __restrict__ DV) {
    int n = blockIdx.x;           // node
    int m = blockIdx.y;           // modality
    int c = threadIdx.x;          // 64 threads = 1 wave
    if (m == 0 && n < 64) DV[n * 64 + c] = 0;   // covers 0..4095
    const float* f = m ? f2 : f1;
    double s = 0.0;
    for (int b = 0; b < BB; ++b) s += (double)f[((size_t)(b * NN) + n) * CC + c];
    double mean = s * 0.25;
    double sq = mean * mean;
    for (int d = 32; d >= 1; d >>= 1) sq += __shfl_xor(sq, d);
    double norm = sqrt(sq);
    if (norm < 1e-12) norm = 1e-12;
    double g = mean / norm;
    g32T[((size_t)m * CC + c) * NN + n] = (float)g;
    gR64[((size_t)m * NN + n) * CC + c] = g;
}

// ---------------------------------------------------------------------------
// 2) f32 sims GEMM, symmetric: compute upper-triangle tiles only (bi<=bj),
//    mirror-write the transpose via LDS bounce.
// ---------------------------------------------------------------------------
__global__ void __launch_bounds__(256)
k_sims(const float* __restrict__ g32T, float* __restrict__ sims) {
    __shared__ float As[CC][64];   // 16 KB
    __shared__ float Bs[CC][64];   // 16 KB
    __shared__ float Cs[64][65];   // 16.25 KB tile bounce (stride 65: no conflicts)
    int m  = blockIdx.y;
    int bi = blockIdx.x >> 5, bj = blockIdx.x & 31;
    if (bi > bj) return;           // symmetric: skip lower triangle
    int i0 = bi * 64, j0 = bj * 64;
    const float* g = g32T + (size_t)m * CC * NN;
    int tid = threadIdx.x;
    #pragma unroll
    for (int q = 0; q < 16; ++q) {
        int idx = q * 256 + tid;
        int k = idx >> 6, r = idx & 63;
        As[k][r] = g[(size_t)k * NN + i0 + r];
        Bs[k][r] = g[(size_t)k * NN + j0 + r];
    }
    __syncthreads();
    int tr = tid >> 4, tc = tid & 15;
    float acc[4][4] = {{0.f}};
    #pragma unroll
    for (int k = 0; k < CC; ++k) {
        float4 a = *((const float4*)&As[k][tr << 2]);
        float4 b = *((const float4*)&Bs[k][tc << 2]);
        acc[0][0] += a.x * b.x; acc[0][1] += a.x * b.y; acc[0][2] += a.x * b.z; acc[0][3] += a.x * b.w;
        acc[1][0] += a.y * b.x; acc[1][1] += a.y * b.y; acc[1][2] += a.y * b.z; acc[1][3] += a.y * b.w;
        acc[2][0] += a.z * b.x; acc[2][1] += a.z * b.y; acc[2][2] += a.z * b.z; acc[2][3] += a.z * b.w;
        acc[3][0] += a.w * b.x; acc[3][1] += a.w * b.y; acc[3][2] += a.w * b.z; acc[3][3] += a.w * b.w;
    }
    float* srow = sims + (size_t)m * NN * NN;
    #pragma unroll
    for (int x = 0; x < 4; ++x) {
        float4 v = make_float4(acc[x][0], acc[x][1], acc[x][2], acc[x][3]);
        *((float4*)&srow[(size_t)(i0 + (tr << 2) + x) * NN + j0 + (tc << 2)]) = v;
        Cs[(tr << 2) + x][(tc << 2) + 0] = acc[x][0];
        Cs[(tr << 2) + x][(tc << 2) + 1] = acc[x][1];
        Cs[(tr << 2) + x][(tc << 2) + 2] = acc[x][2];
        Cs[(tr << 2) + x][(tc << 2) + 3] = acc[x][3];
    }
    __syncthreads();
    #pragma unroll
    for (int q = 0; q < 4; ++q) {
        int idx = q * 256 + tid;
        int cc = idx >> 4, rr4 = (idx & 15) << 2;
        float4 v = make_float4(Cs[rr4 + 0][cc], Cs[rr4 + 1][cc],
                               Cs[rr4 + 2][cc], Cs[rr4 + 3][cc]);
        *((float4*)&srow[(size_t)(j0 + cc) * NN + i0 + rr4]) = v;
    }
}

// ---------------------------------------------------------------------------
// 3) FUSED select+refine. 15-iter binary search (window 6.2e-5; expected
//    extra candidates <<1 vs 13 spare CANDCAP slots; lo stays a valid lower
//    bound of vK_f32 at any iteration count so the superset argument holds).
//    f64 refine dots unrolled 4-wide for ILP across the shuffle chains.
// ---------------------------------------------------------------------------
__global__ void __launch_bounds__(512)
k_selref(const float* __restrict__ sims, const double* __restrict__ gR64,
         int* __restrict__ knn1, int* __restrict__ knn2, int* __restrict__ DV) {
    __shared__ int    candL[8][CANDCAP];
    __shared__ double dotsL[8][CANDCAP];
    int wave = threadIdx.x >> 6, lane = threadIdx.x & 63;
    int row = blockIdx.x * 8 + wave;    // 0..4095
    int m = row >> 11, i = row & 2047;
    int K = m ? 13 : 19;
    const float* s = sims + (size_t)m * NN * NN + (size_t)i * NN;
    float sv[32];
    #pragma unroll
    for (int q = 0; q < 8; ++q) {
        float4 v = *((const float4*)&s[q * 256 + (lane << 2)]);
        sv[q * 4 + 0] = v.x; sv[q * 4 + 1] = v.y; sv[q * 4 + 2] = v.z; sv[q * 4 + 3] = v.w;
    }
    float lo = -1.01f, hi = 1.01f;     // cosine sims live in [-1,1]
    for (int it = 0; it < 15; ++it) {
        float t = 0.5f * (lo + hi);
        int cnt = 0;
        #pragma unroll
        for (int r = 0; r < 32; ++r)
            cnt += __popcll(__ballot(sv[r] >= t));
        if (cnt >= K) lo = t; else hi = t;   // wave-uniform branch
    }
    float thr = lo - 1e-5f;
    unsigned long long ltmask = (lane == 0) ? 0ull : ((~0ull) >> (64 - lane));
    int base = 0;
    #pragma unroll
    for (int r = 0; r < 32; ++r) {
        int j = ((r >> 2) << 8) + (lane << 2) + (r & 3);
        bool p = sv[r] >= thr;
        unsigned long long mk = __ballot(p);
        int ofs = base + __popcll(mk & ltmask);
        if (p && ofs < CANDCAP) candL[wave][ofs] = j;
        base += __popcll(mk);
    }
    int cnt = (base < CANDCAP) ? base : CANDCAP;
    __syncthreads();                       // candL visible
    const double* gm = gR64 + (size_t)m * NN * CC;
    double qc = gm[(size_t)i * CC + lane];
    int t4 = 0;
    for (; t4 + 3 < cnt; t4 += 4) {        // 4 independent reduce chains
        int j0 = candL[wave][t4 + 0], j1 = candL[wave][t4 + 1];
        int j2 = candL[wave][t4 + 2], j3 = candL[wave][t4 + 3];
        double p0 = qc * gm[(size_t)j0 * CC + lane];
        double p1 = qc * gm[(size_t)j1 * CC + lane];
        double p2 = qc * gm[(size_t)j2 * CC + lane];
        double p3 = qc * gm[(size_t)j3 * CC + lane];
        #pragma unroll
        for (int d = 32; d >= 1; d >>= 1) {
            p0 += __shfl_xor(p0, d); p1 += __shfl_xor(p1, d);
            p2 += __shfl_xor(p2, d); p3 += __shfl_xor(p3, d);
        }
        if (lane == 0) {
            dotsL[wave][t4 + 0] = p0; dotsL[wave][t4 + 1] = p1;
            dotsL[wave][t4 + 2] = p2; dotsL[wave][t4 + 3] = p3;
        }
    }
    for (; t4 < cnt; ++t4) {
        int j = candL[wave][t4];
        double p = qc * gm[(size_t)j * CC + lane];
        #pragma unroll
        for (int d = 32; d >= 1; d >>= 1) p += __shfl_xor(p, d);
        if (lane == 0) dotsL[wave][t4] = p;
    }
    __syncthreads();                       // dotsL visible
    int* knn = m ? knn2 : knn1;
    if (lane < cnt) {
        double vt = dotsL[wave][lane]; int jt = candL[wave][lane];
        int rank = 0;
        for (int s2 = 0; s2 < cnt; ++s2) {
            double vs = dotsL[wave][s2]; int js = candL[wave][s2];
            if (vs > vt || (vs == vt && js < jt)) ++rank;
        }
        if (rank < K) {
            knn[(size_t)i * K + rank] = jt;
            int w = (rank < (m ? 5 : 7)) ? 2 : 1;   // member of both edges?
            atomicAdd(&DV[m ? NN + jt : jt], w);
        }
    }
}

// ---------------------------------------------------------------------------
// 4) exclusive scan -> CSR offsets. dvisf = 1/sqrt(DV+1) as f32 (weights only
//    need f32; rel err 6e-8).
// ---------------------------------------------------------------------------
__global__ void k_scan(const int* __restrict__ DV, int* __restrict__ offs,
                       int* __restrict__ cursor, float* __restrict__ dvisf) {
    int lane = threadIdx.x;      // 64
    int base = lane * 64;
    int s = 0;
    for (int q = 0; q < 64; ++q) s += DV[base + q];
    int x = s;
    for (int d = 1; d < 64; d <<= 1) {
        int y = __shfl_up(x, d);
        if (lane >= d) x += y;
    }
    int run = x - s;             // exclusive prefix of lane chunk
    for (int q = 0; q < 64; ++q) {
        int v = base + q;
        offs[v] = run; cursor[v] = run;
        dvisf[v] = (float)(1.0 / sqrt((double)(DV[v] + 1)));
        run += DV[v];
    }
    if (lane == 63) offs[TWO_N] = run;   // == 90112
}

// ---------------------------------------------------------------------------
// 5) fill CSR transpose: node v -> kNN edge ids containing v.
//    families: [0,N) m1k6 ; [N,2N) m1k18 ; [2N,3N) m2k4 ; [3N,4N) m2k12
// ---------------------------------------------------------------------------
__global__ void k_fill(const int* __restrict__ knn1, const int* __restrict__ knn2,
                       int* __restrict__ cursor, int* __restrict__ entries) {
    int id = blockIdx.x * blockDim.x + threadIdx.x;
    const int M1 = NN * 19, M2 = NN * 13;
    if (id < M1) {
        int i = id / 19, t = id % 19;
        int v = knn1[id];
        int p = atomicAdd(&cursor[v], 1); entries[p] = NN + i;       // k=18 edge
        if (t < 7) { int p2 = atomicAdd(&cursor[v], 1); entries[p2] = i; }
    } else if (id < M1 + M2) {
        int id2 = id - M1;
        int i = id2 / 13, t = id2 % 13;
        int v = NN + knn2[id2];
        int p = atomicAdd(&cursor[v], 1); entries[p] = 3 * NN + i;   // k=12 edge
        if (t < 5) { int p2 = atomicAdd(&cursor[v], 1); entries[p2] = 2 * NN + i; }
    }
}

// ---------------------------------------------------------------------------
// 6) LAYER-1 edge stage on RAW x (64-dim): paired kNN edges, prefix-sharing.
//    Grid 2NN x 64 threads. u_x row = 64 floats x 4 batches = 1 KB contiguous.
// ---------------------------------------------------------------------------
__global__ void k_edgeX(const float4* __restrict__ x1, const float4* __restrict__ x2,
                        const float* __restrict__ dvisf,
                        const int* __restrict__ knn1, const int* __restrict__ knn2,
                        float4* __restrict__ u4) {
    __shared__ int mem[19];
    __shared__ float wv[19];
    int blk = blockIdx.x;
    int t = threadIdx.x;            // 64
    int f4 = t & 15, b = t >> 4;    // 16 float4 = 64 feats, 4 batches
    if (blk < NN) {                 // modality-1 pair: k6 (7) + k18 (19)
        if (t < 19) { int v = knn1[(size_t)blk * 19 + t]; mem[t] = v; wv[t] = dvisf[v]; }
        __syncthreads();
        float ax = 0.f, ay = 0.f, az = 0.f, aw = 0.f;
        #pragma unroll
        for (int q = 0; q < 7; ++q) {
            float w = wv[q];
            float4 val = x1[((size_t)(b * NN) + mem[q]) * 16 + f4];
            ax += val.x * w; ay += val.y * w; az += val.z * w; aw += val.w * w;
        }
        const float i7 = 1.f / 49.f;
        u4[(size_t)blk * 64 + t] = make_float4(ax * i7, ay * i7, az * i7, aw * i7);
        #pragma unroll
        for (int q = 7; q < 19; ++q) {
            float w = wv[q];
            float4 val = x1[((size_t)(b * NN) + mem[q]) * 16 + f4];
            ax += val.x * w; ay += val.y * w; az += val.z * w; aw += val.w * w;
        }
        const float i19 = 1.f / 361.f;
        u4[(size_t)(NN + blk) * 64 + t] =
            make_float4(ax * i19, ay * i19, az * i19, aw * i19);
    } else {                        // modality-2 pair: k4 (5) + k12 (13)
        int i = blk - NN;
        if (t < 13) { int j = knn2[(size_t)i * 13 + t]; mem[t] = j; wv[t] = dvisf[NN + j]; }
        __syncthreads();
        float ax = 0.f, ay = 0.f, az = 0.f, aw = 0.f;
        #pragma unroll
        for (int q = 0; q < 5; ++q) {
            float w = wv[q];
            float4 val = x2[((size_t)(b * NN) + mem[q]) * 16 + f4];
            ax += val.x * w; ay += val.y * w; az += val.z * w; aw += val.w * w;
        }
        const float i5 = 1.f / 25.f;
        u4[(size_t)(2 * NN + i) * 64 + t] =
            make_float4(ax * i5, ay * i5, az * i5, aw * i5);
        #pragma unroll
        for (int q = 5; q < 13; ++q) {
            float w = wv[q];
            float4 val = x2[((size_t)(b * NN) + mem[q]) * 16 + f4];
            ax += val.x * w; ay += val.y * w; az += val.z * w; aw += val.w * w;
        }
        const float i13 = 1.f / 169.f;
        u4[(size_t)(3 * NN + i) * 64 + t] =
            make_float4(ax * i13, ay * i13, az * i13, aw * i13);
    }
}

// ---------------------------------------------------------------------------
// 7) LAYER-1 node stage on raw x: aggx[v,b,f64dim] = dvis[v]*(sum u_x + inter).
//    NO relu (relu moves after W1). Output v-major [r'=v*4+b][64].
// ---------------------------------------------------------------------------
__global__ void k_nodeX(const float4* __restrict__ u4,
                        const float4* __restrict__ x1, const float4* __restrict__ x2,
                        const float* __restrict__ dvisf,
                        const int* __restrict__ offs, const int* __restrict__ entries,
                        float4* __restrict__ aggx4) {
    int v = blockIdx.x;
    int t = threadIdx.x;            // 64
    int f4 = t & 15, b = t >> 4;
    int s = offs[v], e_end = offs[v + 1];
    float a0x = 0.f, a0y = 0.f, a0z = 0.f, a0w = 0.f;
    float a1x = 0.f, a1y = 0.f, a1z = 0.f, a1w = 0.f;
    float a2x = 0.f, a2y = 0.f, a2z = 0.f, a2w = 0.f;
    float a3x = 0.f, a3y = 0.f, a3z = 0.f, a3w = 0.f;
    int p = s;
    for (; p + 3 < e_end; p += 4) {
        int e0 = entries[p], e1 = entries[p + 1], e2 = entries[p + 2], e3 = entries[p + 3];
        float4 v0 = u4[(size_t)e0 * 64 + t];
        float4 v1 = u4[(size_t)e1 * 64 + t];
        float4 v2 = u4[(size_t)e2 * 64 + t];
        float4 v3 = u4[(size_t)e3 * 64 + t];
        a0x += v0.x; a0y += v0.y; a0z += v0.z; a0w += v0.w;
        a1x += v1.x; a1y += v1.y; a1z += v1.z; a1w += v1.w;
        a2x += v2.x; a2y += v2.y; a2z += v2.z; a2w += v2.w;
        a3x += v3.x; a3y += v3.y; a3z += v3.z; a3w += v3.w;
    }
    for (; p < e_end; ++p) {
        float4 v0 = u4[(size_t)entries[p] * 64 + t];
        a0x += v0.x; a0y += v0.y; a0z += v0.z; a0w += v0.w;
    }
    float ax = (a0x + a1x) + (a2x + a3x);
    float ay = (a0y + a1y) + (a2y + a3y);
    float az = (a0z + a1z) + (a2z + a3z);
    float aw = (a0w + a1w) + (a2w + a3w);
    // inline inter edge (on raw x)
    int partner = (v < NN) ? v + NN : v - NN;
    float w0 = dvisf[v], w1 = dvisf[partner];
    float4 xv = (v < NN) ? x1[((size_t)(b * NN) + v) * 16 + f4]
                         : x2[((size_t)(b * NN) + (v - NN)) * 16 + f4];
    float4 xp = (partner < NN) ? x1[((size_t)(b * NN) + partner) * 16 + f4]
                               : x2[((size_t)(b * NN) + (partner - NN)) * 16 + f4];
    ax += 0.25f * (xv.x * w0 + xp.x * w1);
    ay += 0.25f * (xv.y * w0 + xp.y * w1);
    az += 0.25f * (xv.z * w0 + xp.z * w1);
    aw += 0.25f * (xv.w * w0 + xp.w * w1);
    ax *= w0; ay *= w0; az *= w0; aw *= w0;
    aggx4[(size_t)v * 64 + t] = make_float4(ax, ay, az, aw);   // v-major, no relu
}

// ---------------------------------------------------------------------------
// 8) z = relu(aggx @ W1^T). f32, K=64 single chunk, 32 rows x 128 cols/block.
//    xT pad 33 (conflict-free scalar broadcast reads), wT pad 132 (16B-aligned
//    rows -> float4 fragment reads, conflict-free).
// ---------------------------------------------------------------------------
__global__ void __launch_bounds__(256)
k_gemm1R(const float* __restrict__ aggx, const float* __restrict__ W1T,
         float* __restrict__ z) {
    __shared__ float xT[64][33];     // 8.4 KB
    __shared__ float wT[64][132];    // 33.8 KB (row = 528 B, 16B-aligned)
    int tid = threadIdx.x;
    int g0 = blockIdx.x * 32;
    #pragma unroll
    for (int q = 0; q < 8; ++q) {            // stage aggx: 32 rows x 64 k
        int idx = q * 256 + tid;
        int row = idx >> 6, k = idx & 63;
        xT[k][row] = aggx[(size_t)(g0 + row) * CC + k];
    }
    #pragma unroll
    for (int q = 0; q < 32; ++q) {           // stage W1T: 64 k x 128 c
        int idx = q * 256 + tid;
        wT[idx >> 7][idx & 127] = W1T[idx];
    }
    __syncthreads();
    int tr = tid >> 5, tc = tid & 31;
    int r0 = tr * 4, c0 = tc * 4;
    float acc[4][4] = {{0.f}};
    #pragma unroll
    for (int k = 0; k < CC; ++k) {
        float xr0 = xT[k][r0 + 0], xr1 = xT[k][r0 + 1];
        float xr2 = xT[k][r0 + 2], xr3 = xT[k][r0 + 3];
        float4 w = *((const float4*)&wT[k][c0]);
        acc[0][0] += xr0 * w.x; acc[0][1] += xr0 * w.y; acc[0][2] += xr0 * w.z; acc[0][3] += xr0 * w.w;
        acc[1][0] += xr1 * w.x; acc[1][1] += xr1 * w.y; acc[1][2] += xr1 * w.z; acc[1][3] += xr1 * w.w;
        acc[2][0] += xr2 * w.x; acc[2][1] += xr2 * w.y; acc[2][2] += xr2 * w.z; acc[2][3] += xr2 * w.w;
        acc[3][0] += xr3 * w.x; acc[3][1] += xr3 * w.y; acc[3][2] += xr3 * w.z; acc[3][3] += xr3 * w.w;
    }
    #pragma unroll
    for (int i = 0; i < 4; ++i) {
        float4 v = make_float4(fmaxf(acc[i][0], 0.f), fmaxf(acc[i][1], 0.f),
                               fmaxf(acc[i][2], 0.f), fmaxf(acc[i][3], 0.f));
        *((float4*)&z[(size_t)(g0 + r0 + i) * HD + c0]) = v;   // relu fused
    }
}

// ---------------------------------------------------------------------------
// 9) y = z @ W2^T (K=128, two 64-k chunks). f32, no relu.
// ---------------------------------------------------------------------------
__global__ void __launch_bounds__(256)
k_gemm2(const float* __restrict__ zin, const float* __restrict__ W2T,
        float* __restrict__ y) {
    __shared__ float zT[64][33];
    __shared__ float wT[64][132];
    int tid = threadIdx.x;
    int g0 = blockIdx.x * 32;
    int tr = tid >> 5, tc = tid & 31;
    int r0 = tr * 4, c0 = tc * 4;
    float acc[4][4] = {{0.f}};
    for (int kc = 0; kc < 2; ++kc) {
        int k0 = kc * 64;
        __syncthreads();
        #pragma unroll
        for (int q = 0; q < 8; ++q) {
            int idx = q * 256 + tid;
            int row = idx >> 6, k = idx & 63;
            zT[k][row] = zin[(size_t)(g0 + row) * HD + k0 + k];
        }
        #pragma unroll
        for (int q = 0; q < 32; ++q) {
            int idx = q * 256 + tid;
            int k = idx >> 7, c = idx & 127;
            wT[k][c] = W2T[(size_t)(k0 + k) * HD + c];
        }
        __syncthreads();
        #pragma unroll
        for (int k = 0; k < 64; ++k) {
            float zr0 = zT[k][r0 + 0], zr1 = zT[k][r0 + 1];
            float zr2 = zT[k][r0 + 2], zr3 = zT[k][r0 + 3];
            float4 w = *((const float4*)&wT[k][c0]);
            acc[0][0] += zr0 * w.x; acc[0][1] += zr0 * w.y; acc[0][2] += zr0 * w.z; acc[0][3] += zr0 * w.w;
            acc[1][0] += zr1 * w.x; acc[1][1] += zr1 * w.y; acc[1][2] += zr1 * w.z; acc[1][3] += zr1 * w.w;
            acc[2][0] += zr2 * w.x; acc[2][1] += zr2 * w.y; acc[2][2] += zr2 * w.z; acc[2][3] += zr2 * w.w;
            acc[3][0] += zr3 * w.x; acc[3][1] += zr3 * w.y; acc[3][2] += zr3 * w.z; acc[3][3] += zr3 * w.w;
        }
    }
    #pragma unroll
    for (int i = 0; i < 4; ++i) {
        float4 v = make_float4(acc[i][0], acc[i][1], acc[i][2], acc[i][3]);
        *((float4*)&y[(size_t)(g0 + r0 + i) * HD + c0]) = v;
    }
}

// ---------------------------------------------------------------------------
// 10) LAYER-2 edge stage on y (128-dim), paired edges, f32. Grid 2NN x 128.
// ---------------------------------------------------------------------------
__global__ void k_edge(const float4* __restrict__ y4, const float* __restrict__ dvisf,
                       const int* __restrict__ knn1, const int* __restrict__ knn2,
                       float4* __restrict__ u4) {
    __shared__ int mem[19];
    __shared__ float wv[19];
    int blk = blockIdx.x;
    int f4 = threadIdx.x & 31;      // float4 feature group
    int b  = threadIdx.x >> 5;      // batch
    int bo = b * 32 + f4;
    int t = threadIdx.x;
    if (blk < NN) {                 // modality-1 pair: k6 (7) + k18 (19)
        if (t < 19) { int v = knn1[(size_t)blk * 19 + t]; mem[t] = v; wv[t] = dvisf[v]; }
        __syncthreads();
        float ax = 0.f, ay = 0.f, az = 0.f, aw = 0.f;
        #pragma unroll
        for (int q = 0; q < 7; ++q) {
            float w = wv[q];
            float4 val = y4[(size_t)mem[q] * 128 + bo];
            ax += val.x * w; ay += val.y * w; az += val.z * w; aw += val.w * w;
        }
        const float i7 = 1.f / 49.f;
        u4[(size_t)blk * 128 + bo] = make_float4(ax * i7, ay * i7, az * i7, aw * i7);
        #pragma unroll
        for (int q = 7; q < 19; ++q) {
            float w = wv[q];
            float4 val = y4[(size_t)mem[q] * 128 + bo];
            ax += val.x * w; ay += val.y * w; az += val.z * w; aw += val.w * w;
        }
        const float i19 = 1.f / 361.f;
        u4[(size_t)(NN + blk) * 128 + bo] =
            make_float4(ax * i19, ay * i19, az * i19, aw * i19);
    } else {                        // modality-2 pair: k4 (5) + k12 (13)
        int i = blk - NN;
        if (t < 13) { int v = NN + knn2[(size_t)i * 13 + t]; mem[t] = v; wv[t] = dvisf[v]; }
        __syncthreads();
        float ax = 0.f, ay = 0.f, az = 0.f, aw = 0.f;
        #pragma unroll
        for (int q = 0; q < 5; ++q) {
            float w = wv[q];
            float4 val = y4[(size_t)mem[q] * 128 + bo];
            ax += val.x * w; ay += val.y * w; az += val.z * w; aw += val.w * w;
        }
        const float i5 = 1.f / 25.f;
        u4[(size_t)(2 * NN + i) * 128 + bo] =
            make_float4(ax * i5, ay * i5, az * i5, aw * i5);
        #pragma unroll
        for (int q = 5; q < 13; ++q) {
            float w = wv[q];
            float4 val = y4[(size_t)mem[q] * 128 + bo];
            ax += val.x * w; ay += val.y * w; az += val.z * w; aw += val.w * w;
        }
        const float i13 = 1.f / 169.f;
        u4[(size_t)(3 * NN + i) * 128 + bo] =
            make_float4(ax * i13, ay * i13, az * i13, aw * i13);
    }
}

// ---------------------------------------------------------------------------
// 11) LAYER-2 node stage, f32, writes the final output (batch-major, split
//     by modality) with relu.
// ---------------------------------------------------------------------------
__global__ void k_node2(const float4* __restrict__ u4, const float4* __restrict__ y4,
                        const float* __restrict__ dvisf,
                        const int* __restrict__ offs, const int* __restrict__ entries,
                        float4* __restrict__ outp4) {
    int v = blockIdx.x;
    int f4 = threadIdx.x & 31;
    int b  = threadIdx.x >> 5;
    int bo = b * 32 + f4;
    int s = offs[v], e_end = offs[v + 1];
    float a0x = 0.f, a0y = 0.f, a0z = 0.f, a0w = 0.f;
    float a1x = 0.f, a1y = 0.f, a1z = 0.f, a1w = 0.f;
    float a2x = 0.f, a2y = 0.f, a2z = 0.f, a2w = 0.f;
    float a3x = 0.f, a3y = 0.f, a3z = 0.f, a3w = 0.f;
    int p = s;
    for (; p + 3 < e_end; p += 4) {
        int e0 = entries[p], e1 = entries[p + 1], e2 = entries[p + 2], e3 = entries[p + 3];
        float4 v0 = u4[(size_t)e0 * 128 + bo];
        float4 v1 = u4[(size_t)e1 * 128 + bo];
        float4 v2 = u4[(size_t)e2 * 128 + bo];
        float4 v3 = u4[(size_t)e3 * 128 + bo];
        a0x += v0.x; a0y += v0.y; a0z += v0.z; a0w += v0.w;
        a1x += v1.x; a1y += v1.y; a1z += v1.z; a1w += v1.w;
        a2x += v2.x; a2y += v2.y; a2z += v2.z; a2w += v2.w;
        a3x += v3.x; a3y += v3.y; a3z += v3.z; a3w += v3.w;
    }
    for (; p < e_end; ++p) {
        float4 v0 = u4[(size_t)entries[p] * 128 + bo];
        a0x += v0.x; a0y += v0.y; a0z += v0.z; a0w += v0.w;
    }
    float ax = (a0x + a1x) + (a2x + a3x);
    float ay = (a0y + a1y) + (a2y + a3y);
    float az = (a0z + a1z) + (a2z + a3z);
    float aw = (a0w + a1w) + (a2w + a3w);
    int partner = (v < NN) ? v + NN : v - NN;
    float w0 = dvisf[v], w1 = dvisf[partner];
    float4 yv = y4[(size_t)v * 128 + bo];
    float4 yp = y4[(size_t)partner * 128 + bo];
    ax += 0.25f * (yv.x * w0 + yp.x * w1);
    ay += 0.25f * (yv.y * w0 + yp.y * w1);
    az += 0.25f * (yv.z * w0 + yp.z * w1);
    aw += 0.25f * (yv.w * w0 + yp.w * w1);
    ax *= w0; ay *= w0; az *= w0; aw *= w0;
    float4 res = make_float4(fmaxf(ax, 0.f), fmaxf(ay, 0.f),
                             fmaxf(az, 0.f), fmaxf(aw, 0.f));
    size_t o;
    if (v < NN) o = ((size_t)(b * NN + v)) * 32 + f4;
    else        o = (size_t)BB * NN * 32 + ((size_t)(b * NN + (v - NN))) * 32 + f4;
    outp4[o] = res;
}

// ---------------------------------------------------------------------------
extern "C" void kernel_launch(void* const* d_in, const int* in_sizes, int n_in,
                              void* d_out, int out_size, void* d_ws, size_t ws_size,
                              hipStream_t stream) {
    const float* f1 = (const float*)d_in[0];
    const float* f2 = (const float*)d_in[1];
    const float* W1 = (const float*)d_in[2];
    const float* W2 = (const float*)d_in[3];
    float* out = (float*)d_out;

    // bump allocator over d_ws
    char* ws = (char*)d_ws;
    size_t off = 0;
    auto alloc = [&](size_t bytes) -> void* {
        void* p = ws + off;
        off = (off + bytes + 255) & ~(size_t)255;
        return p;
    };
    float*  g32T    = (float*)alloc((size_t)2 * CC * NN * 4);         // 1 MB
    double* gR64    = (double*)alloc((size_t)2 * NN * CC * 8);        // 2 MB
    float*  sims    = (float*)alloc((size_t)2 * NN * NN * 4);         // 32 MB
    float*  ybuf    = (float*)alloc((size_t)BB * TWO_N * HD * 4);     // 8 MB  (v-major)
    float*  zbuf    = (float*)alloc((size_t)BB * TWO_N * HD * 4);     // 8 MB  (v-major)
    float*  ubuf    = (float*)alloc((size_t)BB * NE4 * HD * 4);       // 16 MB (e-major; layer1 uses first 8 MB)
    float*  aggx    = (float*)alloc((size_t)BB * TWO_N * CC * 4);     // 4 MB  (v-major, 64-dim)
    float*  W1T     = (float*)alloc((size_t)CC * HD * 4);             // 32 KB
    float*  W2T     = (float*)alloc((size_t)HD * HD * 4);             // 64 KB
    float*  dvisf   = (float*)alloc((size_t)TWO_N * 4);
    int*    knn1    = (int*)alloc((size_t)NN * 19 * 4);
    int*    knn2    = (int*)alloc((size_t)NN * 13 * 4);
    int*    DV      = (int*)alloc((size_t)TWO_N * 4);
    int*    offs    = (int*)alloc((size_t)(TWO_N + 1) * 4);
    int*    cursor  = (int*)alloc((size_t)TWO_N * 4);
    int*    entries = (int*)alloc((size_t)(NN * 26 + NN * 18) * 4);   // 90112

    // graph construction
    k_prep<<<64, 256, 0, stream>>>(W1, W2, W1T, W2T);
    k_mean_norm<<<dim3(NN, 2), 64, 0, stream>>>(f1, f2, g32T, gR64, DV);
    k_sims<<<dim3(32 * 32, 2), 256, 0, stream>>>(g32T, sims);
    k_selref<<<TWO_N / 8, 512, 0, stream>>>(sims, gR64, knn1, knn2, DV);
    k_scan<<<1, 64, 0, stream>>>(DV, offs, cursor, dvisf);
    k_fill<<<(NN * 19 + NN * 13 + 255) / 256, 256, 0, stream>>>(knn1, knn2, cursor, entries);

    // layer 1 (reordered: aggregate raw x, then W1 + relu)
    k_edgeX<<<2 * NN, 64, 0, stream>>>((const float4*)f1, (const float4*)f2, dvisf,
                                       knn1, knn2, (float4*)ubuf);
    k_nodeX<<<TWO_N, 64, 0, stream>>>((const float4*)ubuf, (const float4*)f1,
                                      (const float4*)f2, dvisf, offs, entries,
                                      (float4*)aggx);
    k_gemm1R<<<(BB * TWO_N) / 32, 256, 0, stream>>>(aggx, W1T, zbuf);

    // layer 2
    k_gemm2<<<(BB * TWO_N) / 32, 256, 0, stream>>>(zbuf, W2T, ybuf);
    k_edge<<<2 * NN, 128, 0, stream>>>((const float4*)ybuf, dvisf, knn1, knn2, (float4*)ubuf);
    k_node2<<<TWO_N, 128, 0, stream>>>((const float4*)ubuf, (const float4*)ybuf, dvisf,
                                       offs, entries, (float4*)out);
}